// Round 3
// baseline (644.296 us; speedup 1.0000x reference)
//
#include <hip/hip_runtime.h>

// MeanAggregator: out[b][:] = mean_{s<10} features[neigh_idx[b][s]][:]
// B=50000, S=10, N=1e6, D=128, fp32.
//
// Round-6: DIAGNOSTIC round. The kernel body is byte-identical to round-5
// (SMEM idx loads + saddr-form gathers, which benched 601.3us == baseline).
// kernel_launch enqueues it TWICE back-to-back (idempotent: identical reads,
// identical writes). Purpose: dur_us = fill + 2*k instead of fill + k, so
//   k = dur_r3 - dur_r2   (fill directly observed at ~320us in top-5)
// disambiguates "kernel is ~280us (memory-system cap, keep optimizing)" vs
// "kernel is already ~100us (harness floor, declare roofline)".
// If k > 317us the kernel also enters the rocprof top-5, exposing its
// FETCH_SIZE / Occupancy / VGPR directly.

typedef float v4f __attribute__((ext_vector_type(4)));
typedef int   i4v __attribute__((ext_vector_type(4)));

constexpr int D      = 128;
constexpr int CHUNKS = D / 4;   // 32 lanes per row (float4 chunks)
constexpr int S      = 10;      // num_sample (fixed in reference)

__global__ __launch_bounds__(256, 4)
void mean_agg_kernel(const int* __restrict__ idx,
                     const float* __restrict__ feat,
                     float* __restrict__ out,
                     int halfB)
{
    const int tid  = blockIdx.x * blockDim.x + threadIdx.x;
    const int c    = tid & 31;         // float4 chunk within row
    const int pair = tid >> 5;         // which row-pair
    if (pair >= halfB) return;         // grid is exact for B=50000; safety only

    // Wave-uniform base pair: lanes 0-31 handle pair P0, lanes 32-63 pair P0+1.
    const int  P0 = __builtin_amdgcn_readfirstlane(pair);
    const bool hi = (threadIdx.x & 32) != 0;

    const int* qa = idx + (size_t)P0 * S;                      // rows P0, P0+1
    const int* qb = idx + ((size_t)P0 + (size_t)halfB) * S;    // partner rows

    i4v ia0, ia1, ia2, ia3, ia4, ib0, ib1, ib2, ib3, ib4;
    asm volatile(
        "s_load_dwordx4 %0, %10, 0x0\n\t"
        "s_load_dwordx4 %1, %10, 0x10\n\t"
        "s_load_dwordx4 %2, %10, 0x20\n\t"
        "s_load_dwordx4 %3, %10, 0x30\n\t"
        "s_load_dwordx4 %4, %10, 0x40\n\t"
        "s_load_dwordx4 %5, %11, 0x0\n\t"
        "s_load_dwordx4 %6, %11, 0x10\n\t"
        "s_load_dwordx4 %7, %11, 0x20\n\t"
        "s_load_dwordx4 %8, %11, 0x30\n\t"
        "s_load_dwordx4 %9, %11, 0x40\n\t"
        "s_waitcnt lgkmcnt(0)"
        : "=&s"(ia0), "=&s"(ia1), "=&s"(ia2), "=&s"(ia3), "=&s"(ia4),
          "=&s"(ib0), "=&s"(ib1), "=&s"(ib2), "=&s"(ib3), "=&s"(ib4)
        : "s"(qa), "s"(qb));

    // Unpack to scalar arrays (constant indices after unroll -> SGPRs).
    int A[2 * S], Bq[2 * S];
#pragma unroll
    for (int k = 0; k < 4; ++k) {
        A[k]       = ia0[k]; A[4 + k]   = ia1[k]; A[8 + k]   = ia2[k];
        A[12 + k]  = ia3[k]; A[16 + k]  = ia4[k];
        Bq[k]      = ib0[k]; Bq[4 + k]  = ib1[k]; Bq[8 + k]  = ib2[k];
        Bq[12 + k] = ib3[k]; Bq[16 + k] = ib4[k];
    }

    const unsigned cbyte = (unsigned)c << 4;    // c*16 bytes within the row
    const char* fbase = (const char*)feat;

    // 20 gathers, saddr form: address = uniform base + zext(u32 offset).
    v4f v[2 * S];
#pragma unroll
    for (int s = 0; s < S; ++s) {
        const int      r   = hi ? A[S + s] : A[s];        // cndmask select
        const unsigned off = ((unsigned)r << 9) + cbyte;  // idx*512 + c*16
        v[s] = *(const v4f*)(fbase + (size_t)off);
    }
#pragma unroll
    for (int s = 0; s < S; ++s) {
        const int      r   = hi ? Bq[S + s] : Bq[s];
        const unsigned off = ((unsigned)r << 9) + cbyte;
        v[S + s] = *(const v4f*)(fbase + (size_t)off);
    }

    v4f a0 = (v4f)(0.f);
    v4f a1 = (v4f)(0.f);
#pragma unroll
    for (int s = 0; s < S; ++s) {
        a0 += v[s];
        a1 += v[S + s];
    }

    constexpr float invS = 1.0f / S;
    a0 *= invS;
    a1 *= invS;

    __builtin_nontemporal_store(a0, (v4f*)(out + (size_t)pair * D + c * 4));
    __builtin_nontemporal_store(a1, (v4f*)(out + ((size_t)pair + (size_t)halfB) * D + c * 4));
}

extern "C" void kernel_launch(void* const* d_in, const int* in_sizes, int n_in,
                              void* d_out, int out_size, void* d_ws, size_t ws_size,
                              hipStream_t stream) {
    const int*   idx  = (const int*)d_in[0];    // [B, S] int
    const float* feat = (const float*)d_in[1];  // [N, D] fp32
    float*       out  = (float*)d_out;          // [B, D] fp32

    const int B     = out_size / D;             // 50000
    const int halfB = B / 2;                    // 25000 (B is even)

    const int threads = 256;
    const int total   = halfB * CHUNKS;         // one thread per 2 rows x chunk
    const int blocks  = (total + threads - 1) / threads;

    // DIAGNOSTIC: launch twice (idempotent). dur_us = fill + 2*k -> isolates k.
    mean_agg_kernel<<<blocks, threads, 0, stream>>>(idx, feat, out, halfB);
    mean_agg_kernel<<<blocks, threads, 0, stream>>>(idx, feat, out, halfB);
}

// Round 4
// 602.279 us; speedup vs baseline: 1.0698x; 1.0698x over previous
//
#include <hip/hip_runtime.h>

// MeanAggregator: out[b][:] = mean_{s<10} features[neigh_idx[b][s]][:]
// B=50000, S=10, N=1e6, D=128, fp32.
//
// Round-7 (final): single launch of the round-5 kernel.
// MEASURED (round-6 double-launch diagnostic): the kernel itself runs in
// ~43us (644.3 - 601.3). Compulsory traffic = ~201MB unique feature rows
// (500K draws on 1M rows -> 1M(1-e^-0.5)=393K unique) + 25.6MB out + 2MB idx
// = ~230MB -> 36us at the 6.3TB/s streaming ceiling. 43us = ~85% of that on
// a fully-random 512B-granule gather: at the memory roofline for this
// access pattern. The remaining ~560us of dur_us is harness work (2GB
// poison fills at ~317us each + fixed dispatches), not kernel-controllable.
//
// Kernel structure (verified null-vs-baseline on CU-side variants; kept as
// the cleanest form):
//  - one thread per (row-pair, float4-chunk); lanes 0-31 = pair row P0,
//    lanes 32-63 = row P0+1; partner rows at +halfB.
//  - 40 wave-uniform indices via 10x s_load_dwordx4 (SMEM path).
//  - 20 saddr-form global_load_dwordx4 gathers (base + zext(u32 off)).
//  - accumulate, scale by 1/S, nontemporal stores (out never re-read).

typedef float v4f __attribute__((ext_vector_type(4)));
typedef int   i4v __attribute__((ext_vector_type(4)));

constexpr int D      = 128;
constexpr int CHUNKS = D / 4;   // 32 lanes per row (float4 chunks)
constexpr int S      = 10;      // num_sample (fixed in reference)

__global__ __launch_bounds__(256, 4)
void mean_agg_kernel(const int* __restrict__ idx,
                     const float* __restrict__ feat,
                     float* __restrict__ out,
                     int halfB)
{
    const int tid  = blockIdx.x * blockDim.x + threadIdx.x;
    const int c    = tid & 31;         // float4 chunk within row
    const int pair = tid >> 5;         // which row-pair
    if (pair >= halfB) return;         // grid is exact for B=50000; safety only

    // Wave-uniform base pair: lanes 0-31 handle pair P0, lanes 32-63 pair P0+1.
    const int  P0 = __builtin_amdgcn_readfirstlane(pair);
    const bool hi = (threadIdx.x & 32) != 0;

    const int* qa = idx + (size_t)P0 * S;                      // rows P0, P0+1
    const int* qb = idx + ((size_t)P0 + (size_t)halfB) * S;    // partner rows

    i4v ia0, ia1, ia2, ia3, ia4, ib0, ib1, ib2, ib3, ib4;
    asm volatile(
        "s_load_dwordx4 %0, %10, 0x0\n\t"
        "s_load_dwordx4 %1, %10, 0x10\n\t"
        "s_load_dwordx4 %2, %10, 0x20\n\t"
        "s_load_dwordx4 %3, %10, 0x30\n\t"
        "s_load_dwordx4 %4, %10, 0x40\n\t"
        "s_load_dwordx4 %5, %11, 0x0\n\t"
        "s_load_dwordx4 %6, %11, 0x10\n\t"
        "s_load_dwordx4 %7, %11, 0x20\n\t"
        "s_load_dwordx4 %8, %11, 0x30\n\t"
        "s_load_dwordx4 %9, %11, 0x40\n\t"
        "s_waitcnt lgkmcnt(0)"
        : "=&s"(ia0), "=&s"(ia1), "=&s"(ia2), "=&s"(ia3), "=&s"(ia4),
          "=&s"(ib0), "=&s"(ib1), "=&s"(ib2), "=&s"(ib3), "=&s"(ib4)
        : "s"(qa), "s"(qb));

    // Unpack to scalar arrays (constant indices after unroll -> SGPRs).
    int A[2 * S], Bq[2 * S];
#pragma unroll
    for (int k = 0; k < 4; ++k) {
        A[k]       = ia0[k]; A[4 + k]   = ia1[k]; A[8 + k]   = ia2[k];
        A[12 + k]  = ia3[k]; A[16 + k]  = ia4[k];
        Bq[k]      = ib0[k]; Bq[4 + k]  = ib1[k]; Bq[8 + k]  = ib2[k];
        Bq[12 + k] = ib3[k]; Bq[16 + k] = ib4[k];
    }

    const unsigned cbyte = (unsigned)c << 4;    // c*16 bytes within the row
    const char* fbase = (const char*)feat;

    // 20 gathers, saddr form: address = uniform base + zext(u32 offset).
    v4f v[2 * S];
#pragma unroll
    for (int s = 0; s < S; ++s) {
        const int      r   = hi ? A[S + s] : A[s];        // cndmask select
        const unsigned off = ((unsigned)r << 9) + cbyte;  // idx*512 + c*16
        v[s] = *(const v4f*)(fbase + (size_t)off);
    }
#pragma unroll
    for (int s = 0; s < S; ++s) {
        const int      r   = hi ? Bq[S + s] : Bq[s];
        const unsigned off = ((unsigned)r << 9) + cbyte;
        v[S + s] = *(const v4f*)(fbase + (size_t)off);
    }

    v4f a0 = (v4f)(0.f);
    v4f a1 = (v4f)(0.f);
#pragma unroll
    for (int s = 0; s < S; ++s) {
        a0 += v[s];
        a1 += v[S + s];
    }

    constexpr float invS = 1.0f / S;
    a0 *= invS;
    a1 *= invS;

    __builtin_nontemporal_store(a0, (v4f*)(out + (size_t)pair * D + c * 4));
    __builtin_nontemporal_store(a1, (v4f*)(out + ((size_t)pair + (size_t)halfB) * D + c * 4));
}

extern "C" void kernel_launch(void* const* d_in, const int* in_sizes, int n_in,
                              void* d_out, int out_size, void* d_ws, size_t ws_size,
                              hipStream_t stream) {
    const int*   idx  = (const int*)d_in[0];    // [B, S] int
    const float* feat = (const float*)d_in[1];  // [N, D] fp32
    float*       out  = (float*)d_out;          // [B, D] fp32

    const int B     = out_size / D;             // 50000
    const int halfB = B / 2;                    // 25000 (B is even)

    const int threads = 256;
    const int total   = halfB * CHUNKS;         // one thread per 2 rows x chunk
    const int blocks  = (total + threads - 1) / threads;

    mean_agg_kernel<<<blocks, threads, 0, stream>>>(idx, feat, out, halfB);
}